// Round 2
// baseline (4989.561 us; speedup 1.0000x reference)
//
#include <hip/hip_runtime.h>
#include <hip/hip_bf16.h>

// VQVAE forward: B=1024, IN=256, H=512, E=512, NE=8192, T=32, all fp32.
// out = [recon (1024*256*32), loss (1)]

#define B_ 1024
#define IN_ 256
#define H_ 512
#define E_ 512
#define NE_ 8192
#define T_ 32

// ---------------- weight prep ----------------
// torch Conv1d weight (O,I,3) -> transposed padded layout w4t[i][o] = (k0,k1,k2,0)
__global__ void prep_pad(const float* __restrict__ w, float4* __restrict__ w4t, int O, int ishift) {
    int t = blockIdx.x * 256 + threadIdx.x;  // t = o*I + i
    if (t < (O << ishift)) {
        int o = t >> ishift;
        int i = t & ((1 << ishift) - 1);
        const float* ws = w + (size_t)t * 3;
        float4 v;
        v.x = ws[0];
        v.y = ws[1];
        v.z = ws[2];
        v.w = 0.f;
        w4t[(size_t)i * O + o] = v;
    }
}

// torch ConvTranspose1d weight (I,O,3): conv weight (o,i,kf) = w[i][o][2-kf].
// Source is already i-major, so dest index == t. Just flip the taps.
__global__ void prep_flip(const float* __restrict__ w, float4* __restrict__ w4t, int IO) {
    int t = blockIdx.x * 256 + threadIdx.x;  // t = i*O + o
    if (t < IO) {
        const float* ws = w + (size_t)t * 3;
        float4 v;
        v.x = ws[2];
        v.y = ws[1];
        v.z = ws[0];
        v.w = 0.f;
        w4t[t] = v;
    }
}

// ---------------- conv1d (pad=1, k=3) ----------------
// one block per batch element; input staged in LDS in 256-row chunks; each of
// 128 threads owns OPT=COUT/128 output channels x all 32 time steps in regs.
// Weights read coalesced from w4t[i][o]; next-i weights prefetched.
template <int CIN, int COUT, bool RELU>
__global__ __launch_bounds__(128, 2) void conv_k(const float* __restrict__ x,
                                                 const float4* __restrict__ w4t,
                                                 const float* __restrict__ bias,
                                                 float* __restrict__ y) {
    constexpr int OPT = COUT / 128;
    constexpr int CH = 256;  // input rows per LDS chunk (32 KB)
    __shared__ __align__(16) float xs[CH * 32];
    const int bid = blockIdx.x;
    const int tid = threadIdx.x;

    float acc[OPT][32];
#pragma unroll
    for (int j = 0; j < OPT; ++j) {
        float bv = bias[tid + j * 128];
#pragma unroll
        for (int t = 0; t < 32; ++t) acc[j][t] = bv;
    }

    float4 wcur[OPT];
#pragma unroll
    for (int j = 0; j < OPT; ++j) wcur[j] = w4t[tid + j * 128];

    for (int c0 = 0; c0 < CIN; c0 += CH) {
        const float4* xb4 = (const float4*)(x + ((size_t)bid * CIN + c0) * 32);
        float4* xs4 = (float4*)xs;
        __syncthreads();
        for (int i = tid; i < CH * 8; i += 128) xs4[i] = xb4[i];
        __syncthreads();

#pragma unroll 1
        for (int i = 0; i < CH; ++i) {
            const int ig = c0 + i;
            const int inext = (ig + 1 < CIN) ? ig + 1 : ig;
            float4 wnext[OPT];
#pragma unroll
            for (int j = 0; j < OPT; ++j) wnext[j] = w4t[(size_t)inext * COUT + tid + j * 128];

            float xv[32];
            const float4* xr = (const float4*)(xs + i * 32);
#pragma unroll
            for (int q = 0; q < 8; ++q) {
                float4 v = xr[q];
                xv[q * 4 + 0] = v.x;
                xv[q * 4 + 1] = v.y;
                xv[q * 4 + 2] = v.z;
                xv[q * 4 + 3] = v.w;
            }
#pragma unroll
            for (int j = 0; j < OPT; ++j) {
                float4 w = wcur[j];
#pragma unroll
                for (int t = 0; t < 32; ++t) {
                    float s = acc[j][t];
                    if (t > 0) s += w.x * xv[t - 1];
                    s += w.y * xv[t];
                    if (t < 31) s += w.z * xv[t + 1];
                    acc[j][t] = s;
                }
            }
#pragma unroll
            for (int j = 0; j < OPT; ++j) wcur[j] = wnext[j];
        }
    }

#pragma unroll
    for (int j = 0; j < OPT; ++j) {
        float* yo = y + ((size_t)bid * COUT + (tid + j * 128)) * 32;
#pragma unroll
        for (int q = 0; q < 8; ++q) {
            float4 v;
            v.x = acc[j][q * 4 + 0];
            v.y = acc[j][q * 4 + 1];
            v.z = acc[j][q * 4 + 2];
            v.w = acc[j][q * 4 + 3];
            if (RELU) {
                v.x = fmaxf(v.x, 0.f);
                v.y = fmaxf(v.y, 0.f);
                v.z = fmaxf(v.z, 0.f);
                v.w = fmaxf(v.w, 0.f);
            }
            ((float4*)yo)[q] = v;
        }
    }
}

// ---------------- TN GEMM: C[m,n] = sum_k A[m,k]*Bm[n,k] (+bias[n]) ----------------
// 128x128 tile, BK=16, 256 threads, 8x8 microtile. Optional split-K over
// blockIdx.z (each slice kslice wide, output offset slice*M*N). Dims are exact
// multiples (M%128==0, N%128==0, kslice%16==0).
template <bool BIAS>
__global__ __launch_bounds__(256) void gemm_tn(const float* __restrict__ A,
                                               const float* __restrict__ Bm,
                                               const float* __restrict__ bias,
                                               float* __restrict__ C, int N, int K, int kslice) {
    __shared__ __align__(16) float As[16][132];
    __shared__ __align__(16) float Bs[16][132];
    const int n0 = blockIdx.x * 128;
    const int m0 = blockIdx.y * 128;
    const int M = gridDim.y * 128;
    const int tid = threadIdx.x;
    const int tx = tid & 15;   // n dir
    const int ty = tid >> 4;   // m dir
    const int kbeg = blockIdx.z * kslice;
    float acc[8][8] = {};

    for (int k0 = kbeg; k0 < kbeg + kslice; k0 += 16) {
#pragma unroll
        for (int l = 0; l < 2; ++l) {
            int t = tid + l * 256;
            int r = t >> 2;
            int c = (t & 3) << 2;
            float4 va = *(const float4*)(A + (size_t)(m0 + r) * K + k0 + c);
            As[c + 0][r] = va.x;
            As[c + 1][r] = va.y;
            As[c + 2][r] = va.z;
            As[c + 3][r] = va.w;
            float4 vb = *(const float4*)(Bm + (size_t)(n0 + r) * K + k0 + c);
            Bs[c + 0][r] = vb.x;
            Bs[c + 1][r] = vb.y;
            Bs[c + 2][r] = vb.z;
            Bs[c + 3][r] = vb.w;
        }
        __syncthreads();
#pragma unroll
        for (int k = 0; k < 16; ++k) {
            float a[8], b[8];
            *(float4*)&a[0] = *(const float4*)&As[k][ty * 8];
            *(float4*)&a[4] = *(const float4*)&As[k][ty * 8 + 4];
            *(float4*)&b[0] = *(const float4*)&Bs[k][tx * 8];
            *(float4*)&b[4] = *(const float4*)&Bs[k][tx * 8 + 4];
#pragma unroll
            for (int i = 0; i < 8; ++i)
#pragma unroll
                for (int j = 0; j < 8; ++j) acc[i][j] += a[i] * b[j];
        }
        __syncthreads();
    }

    float bv[8];
#pragma unroll
    for (int j = 0; j < 8; ++j) bv[j] = 0.f;
    if (BIAS) {
        *(float4*)&bv[0] = *(const float4*)(bias + n0 + tx * 8);
        *(float4*)&bv[4] = *(const float4*)(bias + n0 + tx * 8 + 4);
    }
    float* Cp = C + (size_t)blockIdx.z * M * N;
#pragma unroll
    for (int i = 0; i < 8; ++i) {
        float* crow = Cp + (size_t)(m0 + ty * 8 + i) * N + n0 + tx * 8;
        float4 v0, v1;
        v0.x = acc[i][0] + bv[0];
        v0.y = acc[i][1] + bv[1];
        v0.z = acc[i][2] + bv[2];
        v0.w = acc[i][3] + bv[3];
        v1.x = acc[i][4] + bv[4];
        v1.y = acc[i][5] + bv[5];
        v1.z = acc[i][6] + bv[6];
        v1.w = acc[i][7] + bv[7];
        *(float4*)crow = v0;
        *(float4*)(crow + 4) = v1;
    }
}

// sum split-K partials + bias -> z
__global__ void reduce_bias(const float4* __restrict__ part, const float* __restrict__ bias,
                            float4* __restrict__ z, int slices) {
    int t = blockIdx.x * 256 + threadIdx.x;  // over B_*E_/4
    const int stride = B_ * E_ / 4;
    float4 a = part[t];
#pragma unroll 4
    for (int s = 1; s < slices; ++s) {
        float4 p = part[(size_t)s * stride + t];
        a.x += p.x;
        a.y += p.y;
        a.z += p.z;
        a.w += p.w;
    }
    float4 bv = ((const float4*)bias)[t & (E_ / 4 - 1)];
    a.x += bv.x;
    a.y += bv.y;
    a.z += bv.z;
    a.w += bv.w;
    z[t] = a;
}

// ---------------- VQ ----------------
__global__ void cnorm_k(const float* __restrict__ cb, float* __restrict__ cnorm) {
    int n = blockIdx.x;
    int l = threadIdx.x;  // 64 threads
    const float4* row = (const float4*)(cb + (size_t)n * E_);
    float s = 0.f;
#pragma unroll
    for (int q = 0; q < 2; ++q) {
        float4 v = row[l + q * 64];
        s += v.x * v.x + v.y * v.y + v.z * v.z + v.w * v.w;
    }
#pragma unroll
    for (int off = 32; off; off >>= 1) s += __shfl_down(s, off);
    if (l == 0) cnorm[n] = s;
}

// scores = 2*z@cb^T - cnorm; per-row argmax within 128-col tile -> partials.
// Same 128x128/8x8 structure as gemm_tn; K = E_ = 512.
__global__ __launch_bounds__(256) void vq_score(const float* __restrict__ z,
                                                const float* __restrict__ cb,
                                                const float* __restrict__ cnorm,
                                                float* __restrict__ pval, int* __restrict__ pidx) {
    __shared__ __align__(16) float smem[2 * 16 * 132];
    float (*As)[132] = (float(*)[132])smem;
    float (*Bs)[132] = (float(*)[132])(smem + 16 * 132);
    const int n0 = blockIdx.x * 128;
    const int m0 = blockIdx.y * 128;
    const int tid = threadIdx.x;
    const int tx = tid & 15;
    const int ty = tid >> 4;
    float acc[8][8] = {};

    for (int k0 = 0; k0 < E_; k0 += 16) {
#pragma unroll
        for (int l = 0; l < 2; ++l) {
            int t = tid + l * 256;
            int r = t >> 2;
            int c = (t & 3) << 2;
            float4 va = *(const float4*)(z + (size_t)(m0 + r) * E_ + k0 + c);
            As[c + 0][r] = va.x;
            As[c + 1][r] = va.y;
            As[c + 2][r] = va.z;
            As[c + 3][r] = va.w;
            float4 vb = *(const float4*)(cb + (size_t)(n0 + r) * E_ + k0 + c);
            Bs[c + 0][r] = vb.x;
            Bs[c + 1][r] = vb.y;
            Bs[c + 2][r] = vb.z;
            Bs[c + 3][r] = vb.w;
        }
        __syncthreads();
#pragma unroll
        for (int k = 0; k < 16; ++k) {
            float a[8], b[8];
            *(float4*)&a[0] = *(const float4*)&As[k][ty * 8];
            *(float4*)&a[4] = *(const float4*)&As[k][ty * 8 + 4];
            *(float4*)&b[0] = *(const float4*)&Bs[k][tx * 8];
            *(float4*)&b[4] = *(const float4*)&Bs[k][tx * 8 + 4];
#pragma unroll
            for (int i = 0; i < 8; ++i)
#pragma unroll
                for (int j = 0; j < 8; ++j) acc[i][j] += a[i] * b[j];
        }
        __syncthreads();
    }

    // reuse smem for the argmax reduction (post final sync; 2048 <= 2112 each)
    float* sv = smem;
    int* si = (int*)(smem + 16 * 132);
    float cn[8];
    *(float4*)&cn[0] = *(const float4*)(cnorm + n0 + tx * 8);
    *(float4*)&cn[4] = *(const float4*)(cnorm + n0 + tx * 8 + 4);
#pragma unroll
    for (int i = 0; i < 8; ++i) {
        int row = ty * 8 + i;
        float bv = -3.4e38f;
        int bn = 0;
#pragma unroll
        for (int j = 0; j < 8; ++j) {
            float v = 2.f * acc[i][j] - cn[j];
            if (v > bv) { bv = v; bn = n0 + tx * 8 + j; }
        }
        sv[row * 16 + tx] = bv;
        si[row * 16 + tx] = bn;
    }
    __syncthreads();
    if (tid < 128) {
        float bv = sv[tid * 16];
        int bn = si[tid * 16];
#pragma unroll
        for (int t = 1; t < 16; ++t) {
            float v = sv[tid * 16 + t];
            if (v > bv) { bv = v; bn = si[tid * 16 + t]; }
        }
        pval[(size_t)(m0 + tid) * 64 + blockIdx.x] = bv;
        pidx[(size_t)(m0 + tid) * 64 + blockIdx.x] = bn;
    }
}

__global__ void vq_final(const float* __restrict__ pval, const int* __restrict__ pidx,
                         int* __restrict__ idx) {
    int b = blockIdx.x * 256 + threadIdx.x;
    if (b < B_) {
        const float* pv = pval + (size_t)b * 64;
        const int* pi = pidx + (size_t)b * 64;
        float bv = pv[0];
        int bn = pi[0];
        for (int t = 1; t < 64; ++t) {
            float v = pv[t];
            if (v > bv) { bv = v; bn = pi[t]; }
        }
        idx[b] = bn;
    }
}

// gather z_q = codebook[idx] and per-row sum (zq - z)^2
__global__ __launch_bounds__(128) void zq_loss(const float* __restrict__ z,
                                               const float* __restrict__ cb,
                                               const int* __restrict__ idx,
                                               float* __restrict__ zq, float* __restrict__ lsum) {
    int b = blockIdx.x;
    int t = threadIdx.x;  // 128 threads, one float4 each
    int id = idx[b];
    float4 c = ((const float4*)(cb + (size_t)id * E_))[t];
    ((float4*)(zq + (size_t)b * E_))[t] = c;
    float4 zv = ((const float4*)(z + (size_t)b * E_))[t];
    float dx = c.x - zv.x, dy = c.y - zv.y, dz = c.z - zv.z, dw = c.w - zv.w;
    float s = dx * dx + dy * dy + dz * dz + dw * dw;
#pragma unroll
    for (int off = 32; off; off >>= 1) s += __shfl_down(s, off);
    __shared__ float w2[2];
    if ((t & 63) == 0) w2[t >> 6] = s;
    __syncthreads();
    if (t == 0) lsum[b] = w2[0] + w2[1];
}

__global__ void loss_final(const float* __restrict__ lsum, float* __restrict__ out) {
    __shared__ float sm[256];
    float s = 0.f;
    for (int i = threadIdx.x; i < B_; i += 256) s += lsum[i];
    sm[threadIdx.x] = s;
    __syncthreads();
    for (int off = 128; off; off >>= 1) {
        if (threadIdx.x < off) sm[threadIdx.x] += sm[threadIdx.x + off];
        __syncthreads();
    }
    if (threadIdx.x == 0) out[0] = 1.25f * sm[0] / (float)(B_ * E_);
}

// ---------------- launcher ----------------
extern "C" void kernel_launch(void* const* d_in, const int* in_sizes, int n_in,
                              void* d_out, int out_size, void* d_ws, size_t ws_size,
                              hipStream_t stream) {
    const float* x = (const float*)d_in[0];
    const float* ew1 = (const float*)d_in[1];
    const float* eb1 = (const float*)d_in[2];
    const float* ew2 = (const float*)d_in[3];
    const float* eb2 = (const float*)d_in[4];
    const float* ew3 = (const float*)d_in[5];
    const float* eb3 = (const float*)d_in[6];
    const float* ew4 = (const float*)d_in[7];
    const float* eb4 = (const float*)d_in[8];
    const float* efw = (const float*)d_in[9];
    const float* efb = (const float*)d_in[10];
    const float* cb = (const float*)d_in[11];
    const float* dfw = (const float*)d_in[12];
    const float* dfb = (const float*)d_in[13];
    const float* dw4 = (const float*)d_in[14];
    const float* db4 = (const float*)d_in[15];
    const float* dw3 = (const float*)d_in[16];
    const float* db3 = (const float*)d_in[17];
    const float* dw2 = (const float*)d_in[18];
    const float* db2 = (const float*)d_in[19];
    const float* dw1 = (const float*)d_in[20];
    const float* db1 = (const float*)d_in[21];
    float* out = (float*)d_out;

    // workspace layout (floats)
    float* ws = (float*)d_ws;
    float* buf0 = ws;                           // B*H*T = 16,777,216 (also split-K partials)
    float* buf1 = buf0 + (size_t)B_ * H_ * T_;  // 16,777,216
    float* z = buf1 + (size_t)B_ * H_ * T_;     // 524,288
    float* zq = z + (size_t)B_ * E_;            // 524,288
    float* cnorm = zq + (size_t)B_ * E_;        // 8,192
    float* pval = cnorm + NE_;                  // B*64 = 65,536
    int* pidx = (int*)(pval + (size_t)B_ * 64); // 65,536
    int* idx = pidx + (size_t)B_ * 64;          // 1,024
    float* lsum = (float*)(idx + B_);           // 1,024
    float4* ew1p = (float4*)(lsum + B_);        // IN*H float4
    float4* ew2p = ew1p + (size_t)H_ * IN_;     // H*H float4 each
    float4* ew3p = ew2p + (size_t)H_ * H_;
    float4* ew4p = ew3p + (size_t)H_ * H_;
    float4* dw4p = ew4p + (size_t)H_ * H_;
    float4* dw3p = dw4p + (size_t)H_ * H_;
    float4* dw2p = dw3p + (size_t)H_ * H_;
    float4* dw1p = dw2p + (size_t)H_ * H_;

    // weight prep (transposed [i][o] layout for coalesced conv reads)
    prep_pad<<<(H_ * IN_ + 255) / 256, 256, 0, stream>>>(ew1, ew1p, H_, 8);
    prep_pad<<<(H_ * H_ + 255) / 256, 256, 0, stream>>>(ew2, ew2p, H_, 9);
    prep_pad<<<(H_ * H_ + 255) / 256, 256, 0, stream>>>(ew3, ew3p, H_, 9);
    prep_pad<<<(H_ * H_ + 255) / 256, 256, 0, stream>>>(ew4, ew4p, H_, 9);
    prep_flip<<<(H_ * H_ + 255) / 256, 256, 0, stream>>>(dw4, dw4p, H_ * H_);
    prep_flip<<<(H_ * H_ + 255) / 256, 256, 0, stream>>>(dw3, dw3p, H_ * H_);
    prep_flip<<<(H_ * H_ + 255) / 256, 256, 0, stream>>>(dw2, dw2p, H_ * H_);
    prep_flip<<<(H_ * IN_ + 255) / 256, 256, 0, stream>>>(dw1, dw1p, H_ * IN_);

    // encoder
    conv_k<IN_, H_, true><<<B_, 128, 0, stream>>>(x, ew1p, eb1, buf0);
    conv_k<H_, H_, true><<<B_, 128, 0, stream>>>(buf0, ew2p, eb2, buf1);
    conv_k<H_, H_, true><<<B_, 128, 0, stream>>>(buf1, ew3p, eb3, buf0);
    conv_k<H_, H_, true><<<B_, 128, 0, stream>>>(buf0, ew4p, eb4, buf1);
    // encoder FC: M=1024, N=512, K=16384, split-K=16 -> partials in buf0
    gemm_tn<false><<<dim3(E_ / 128, B_ / 128, 16), 256, 0, stream>>>(buf1, efw, nullptr, buf0,
                                                                    E_, H_ * T_, H_ * T_ / 16);
    reduce_bias<<<(B_ * E_ / 4) / 256, 256, 0, stream>>>((const float4*)buf0, efb, (float4*)z, 16);

    // VQ
    cnorm_k<<<NE_, 64, 0, stream>>>(cb, cnorm);
    vq_score<<<dim3(NE_ / 128, B_ / 128), 256, 0, stream>>>(z, cb, cnorm, pval, pidx);
    vq_final<<<(B_ + 255) / 256, 256, 0, stream>>>(pval, pidx, idx);
    zq_loss<<<B_, 128, 0, stream>>>(z, cb, idx, zq, lsum);
    loss_final<<<1, 256, 0, stream>>>(lsum, out + (size_t)B_ * IN_ * T_);

    // decoder FC: M=1024, N=16384, K=512
    gemm_tn<true><<<dim3((H_ * T_) / 128, B_ / 128, 1), 256, 0, stream>>>(zq, dfw, dfb, buf0,
                                                                          H_ * T_, E_, E_);
    conv_k<H_, H_, true><<<B_, 128, 0, stream>>>(buf0, dw4p, db4, buf1);
    conv_k<H_, H_, true><<<B_, 128, 0, stream>>>(buf1, dw3p, db3, buf0);
    conv_k<H_, H_, true><<<B_, 128, 0, stream>>>(buf0, dw2p, db2, buf1);
    conv_k<H_, IN_, false><<<B_, 128, 0, stream>>>(buf1, dw1p, db1, out);
}

// Round 3
// 2394.312 us; speedup vs baseline: 2.0839x; 2.0839x over previous
//
#include <hip/hip_runtime.h>
#include <hip/hip_bf16.h>

// VQVAE forward: B=1024, IN=256, H=512, E=512, NE=8192, T=32.
// MFMA split-bf16 (hi/lo) path for convs + FCs; fp32 VALU for VQ scoring.

#define B_ 1024
#define IN_ 256
#define H_ 512
#define E_ 512
#define NE_ 8192
#define T_ 32

typedef __attribute__((ext_vector_type(8))) short short8;
typedef __attribute__((ext_vector_type(4))) short short4v;
typedef __attribute__((ext_vector_type(4))) float f32x4;

__device__ __forceinline__ unsigned short bf_hi(float v) {
    __hip_bfloat16 h = __float2bfloat16(v);
    return *reinterpret_cast<unsigned short*>(&h);
}
__device__ __forceinline__ float bf_f(unsigned short u) {
    __hip_bfloat16 h;
    *reinterpret_cast<unsigned short*>(&h) = u;
    return __bfloat162float(h);
}
__device__ __forceinline__ void split2(float v, unsigned short& h, unsigned short& l) {
    h = bf_hi(v);
    l = bf_hi(v - bf_f(h));
}

// ---------------- transpose + hi/lo split ----------------
// src: [outer][R=256*chunks][32] fp32 -> dst planes [outer][32][R] bf16 hi/lo
// (d_rstride = R total per output row)
__global__ __launch_bounds__(256) void transpose_split(const float* __restrict__ src,
        unsigned short* __restrict__ dh, unsigned short* __restrict__ dl,
        int chunks, size_t s_outer, size_t d_outer, int d_rstride) {
    __shared__ float xs[256][33];
    const int ch = blockIdx.x % chunks;
    const int ou = blockIdx.x / chunks;
    const int tid = threadIdx.x;
    const float4* s4 = (const float4*)(src + (size_t)ou * s_outer + (size_t)ch * 256 * 32);
#pragma unroll
    for (int q = 0; q < 8; ++q) {
        float4 v = s4[tid * 8 + q];
        xs[tid][q * 4 + 0] = v.x;
        xs[tid][q * 4 + 1] = v.y;
        xs[tid][q * 4 + 2] = v.z;
        xs[tid][q * 4 + 3] = v.w;
    }
    __syncthreads();
    const int t = tid & 31, ig = tid >> 5;
#pragma unroll
    for (int g2 = 0; g2 < 4; ++g2) {
        int i0 = (ig + g2 * 8) * 8;
        short8 hv, lv;
#pragma unroll
        for (int j = 0; j < 8; ++j) {
            float v = xs[i0 + j][t];
            unsigned short hh, ll;
            split2(v, hh, ll);
            hv[j] = (short)hh;
            lv[j] = (short)ll;
        }
        size_t off = (size_t)ou * d_outer + (size_t)ch * 256 + (size_t)t * d_rstride + i0;
        *(short8*)(dh + off) = hv;
        *(short8*)(dl + off) = lv;
    }
}

// ---------------- weight preps ----------------
// Conv1d (O,I,3) fp32 -> [tap][o][i] bf16 hi/lo
__global__ void wprep_conv(const float* __restrict__ w, unsigned short* __restrict__ wh,
                           unsigned short* __restrict__ wl, int O, int I) {
    int t = blockIdx.x * 256 + threadIdx.x;
    if (t < O * I) {
        int OI = O * I;
#pragma unroll
        for (int tap = 0; tap < 3; ++tap) {
            float v = w[(size_t)t * 3 + tap];
            unsigned short hh, ll;
            split2(v, hh, ll);
            wh[(size_t)tap * OI + t] = hh;
            wl[(size_t)tap * OI + t] = ll;
        }
    }
}
// ConvTranspose1d (I,O,3): conv w[tap][o][i] = src[i][o][2-tap]
__global__ void wprep_deconv(const float* __restrict__ w, unsigned short* __restrict__ wh,
                             unsigned short* __restrict__ wl, int O, int I) {
    int t = blockIdx.x * 256 + threadIdx.x;
    if (t < O * I) {
        int o = t / I, i = t % I;
        int OI = O * I;
#pragma unroll
        for (int tap = 0; tap < 3; ++tap) {
            float v = w[((size_t)i * O + o) * 3 + 2 - tap];
            unsigned short hh, ll;
            split2(v, hh, ll);
            wh[(size_t)tap * OI + t] = hh;
            wl[(size_t)tap * OI + t] = ll;
        }
    }
}
// dfw (16384,512) f=c*32+t -> [f'=t*512+c][e] bf16 hi/lo
__global__ void wprep_dfw(const float* __restrict__ w, unsigned short* __restrict__ wh,
                          unsigned short* __restrict__ wl) {
    size_t id = (size_t)blockIdx.x * 256 + threadIdx.x;  // < 16384*64
    int fp = (int)(id >> 6);
    int e8 = ((int)id & 63) * 8;
    int tt = fp >> 9, c = fp & 511;
    int f = c * 32 + tt;
    const float* s = w + (size_t)f * 512 + e8;
    short8 hv, lv;
#pragma unroll
    for (int j = 0; j < 8; ++j) {
        unsigned short hh, ll;
        split2(s[j], hh, ll);
        hv[j] = (short)hh;
        lv[j] = (short)ll;
    }
    *(short8*)(wh + (size_t)fp * 512 + e8) = hv;
    *(short8*)(wl + (size_t)fp * 512 + e8) = lv;
}
__global__ void wprep_dfb(const float* __restrict__ b, float* __restrict__ bp) {
    int fp = blockIdx.x * 256 + threadIdx.x;  // 16384
    int tt = fp >> 9, c = fp & 511;
    bp[fp] = b[c * 32 + tt];
}

// ---------------- conv1d via MFMA implicit GEMM ----------------
// Activations: planes [b][t][CIN] bf16 hi/lo. Weights: [tap][o][i] hi/lo.
// Block = 4 batches (128 (b,t) cols), 8 waves. Wave = 64 o x (128 or 64) cols.
// Output: bf16 hi/lo planes [b][t][COUT] (+bias,+relu) or fp32 [b][o][t] (no relu).
template <int CIN, int COUT, bool FP32OUT>
__global__ __launch_bounds__(512, 2) void conv_mfma(
    const unsigned short* __restrict__ Xh, const unsigned short* __restrict__ Xl,
    const unsigned short* __restrict__ Wh, const unsigned short* __restrict__ Wl,
    const float* __restrict__ bias,
    unsigned short* __restrict__ Yh, unsigned short* __restrict__ Yl,
    float* __restrict__ Yf) {
    constexpr int NSTEP = CIN / 32;
    constexpr int NF = (COUT == 512) ? 8 : 4;
    __shared__ short Bs[2][2][136][40];  // [buf][plane][row][i] 43.5 KB

    const int tid = threadIdx.x;
    const int wid = tid >> 6;
    const int lane = tid & 63;
    const int l15 = lane & 15;
    const int lg = lane >> 4;
    const int b0 = blockIdx.x * 4;

    const int of_base = (COUT == 512) ? wid * 64 : (wid >> 1) * 64;
    const int nf0 = (COUT == 512) ? 0 : (wid & 1) * 4;

    // zero the pad rows (t=-1 / t=32 per batch group) in both buffers/planes
    for (int j = tid; j < 32 * 40; j += 512) {
        int row_id = j / 40, col = j % 40;
        int buf = row_id >> 4, pl = (row_id >> 3) & 1, rz = row_id & 7;
        int c = (rz >> 1) * 34 + (rz & 1) * 33;
        Bs[buf][pl][c][col] = 0;
    }

    f32x4 acc[4][NF];
#pragma unroll
    for (int of = 0; of < 4; ++of)
#pragma unroll
        for (int nf = 0; nf < NF; ++nf) acc[of][nf] = (f32x4){0.f, 0.f, 0.f, 0.f};

    // staging map: 512 threads -> 128 rows x 4 i-quads, per plane
    const int srow = tid >> 2;
    const int sq = tid & 3;
    const int sb = srow >> 5, st = srow & 31;
    const size_t src_off = (((size_t)(b0 + sb) * 32) + st) * CIN + sq * 8;
    const int sc = sb * 34 + 1 + st;

    {
        short8 h0 = *(const short8*)(Xh + src_off);
        short8 l0 = *(const short8*)(Xl + src_off);
        *(short8*)&Bs[0][0][sc][sq * 8] = h0;
        *(short8*)&Bs[0][1][sc][sq * 8] = l0;
    }
    __syncthreads();

    for (int ks = 0; ks < NSTEP; ++ks) {
        const int i0 = ks * 32;
        const int buf = ks & 1;
        short8 nh, nl;
        const bool pre = (ks + 1 < NSTEP);
        if (pre) {
            nh = *(const short8*)(Xh + src_off + i0 + 32);
            nl = *(const short8*)(Xl + src_off + i0 + 32);
        }
#pragma unroll
        for (int tap = 0; tap < 3; ++tap) {
            short8 Ah[4], Al[4];
#pragma unroll
            for (int of = 0; of < 4; ++of) {
                const size_t wo =
                    ((size_t)tap * COUT + of_base + of * 16 + l15) * CIN + i0 + lg * 8;
                Ah[of] = *(const short8*)(Wh + wo);
                Al[of] = *(const short8*)(Wl + wo);
            }
#pragma unroll
            for (int nf = 0; nf < NF; ++nf) {
                const int nfg = nf0 + nf;
                const int row = (nfg >> 1) * 34 + (nfg & 1) * 16 + tap + l15;
                short8 Bh = *(const short8*)&Bs[buf][0][row][lg * 8];
                short8 Bl = *(const short8*)&Bs[buf][1][row][lg * 8];
#pragma unroll
                for (int of = 0; of < 4; ++of) {
                    acc[of][nf] =
                        __builtin_amdgcn_mfma_f32_16x16x32_bf16(Ah[of], Bh, acc[of][nf], 0, 0, 0);
                    acc[of][nf] =
                        __builtin_amdgcn_mfma_f32_16x16x32_bf16(Ah[of], Bl, acc[of][nf], 0, 0, 0);
                    acc[of][nf] =
                        __builtin_amdgcn_mfma_f32_16x16x32_bf16(Al[of], Bh, acc[of][nf], 0, 0, 0);
                }
            }
        }
        if (pre) {
            *(short8*)&Bs[buf ^ 1][0][sc][sq * 8] = nh;
            *(short8*)&Bs[buf ^ 1][1][sc][sq * 8] = nl;
        }
        __syncthreads();
    }

    // epilogue: D lane holds cols n=l15 (per nf), rows m = of*16 + 4*lg + r
#pragma unroll
    for (int of = 0; of < 4; ++of) {
        const int m4 = of_base + of * 16 + lg * 4;
        float4 bv = *(const float4*)(bias + m4);
        float bva[4] = {bv.x, bv.y, bv.z, bv.w};
#pragma unroll
        for (int nf = 0; nf < NF; ++nf) {
            const int n = (nf0 + nf) * 16 + l15;
            const int gb = b0 + (n >> 5);
            const int t = n & 31;
            if (FP32OUT) {
#pragma unroll
                for (int r = 0; r < 4; ++r) {
                    float v = acc[of][nf][r] + bva[r];
                    Yf[((size_t)gb * COUT + m4 + r) * 32 + t] = v;
                }
            } else {
                short4v hv, lv;
#pragma unroll
                for (int r = 0; r < 4; ++r) {
                    float v = fmaxf(acc[of][nf][r] + bva[r], 0.f);
                    unsigned short hh, ll;
                    split2(v, hh, ll);
                    hv[r] = (short)hh;
                    lv[r] = (short)ll;
                }
                const size_t off = ((size_t)gb * 32 + t) * COUT + m4;
                *(short4v*)(Yh + off) = hv;
                *(short4v*)(Yl + off) = lv;
            }
        }
    }
}

// ---------------- FC via MFMA (global-fragment GEMM-TN) ----------------
// C[m,n] = sum_k A[m,k]*B[n,k], 3-term split-bf16. Block 256x256, 8 waves.
// MODE 0: fp32 partial (split-K, layout [kz][n][m]); MODE 1: +bias, hi/lo out [n][m].
template <int MODE>
__global__ __launch_bounds__(512, 2) void fc_mfma(
    const unsigned short* __restrict__ Ah_, const unsigned short* __restrict__ Al_,
    const unsigned short* __restrict__ Bh_, const unsigned short* __restrict__ Bl_,
    const float* __restrict__ bias, float* __restrict__ Pf,
    unsigned short* __restrict__ Oh, unsigned short* __restrict__ Ol,
    int M, int N, int K, int kc) {
    const int tid = threadIdx.x;
    const int wid = tid >> 6;
    const int lane = tid & 63;
    const int l15 = lane & 15;
    const int lg = lane >> 4;
    const int m0 = blockIdx.y * 256 + (wid & 3) * 64;
    const int n0 = blockIdx.x * 256 + (wid >> 2) * 128;
    const int k0b = blockIdx.z * kc;

    f32x4 acc[4][8];
#pragma unroll
    for (int of = 0; of < 4; ++of)
#pragma unroll
        for (int nf = 0; nf < 8; ++nf) acc[of][nf] = (f32x4){0.f, 0.f, 0.f, 0.f};

    for (int k0 = k0b; k0 < k0b + kc; k0 += 32) {
        short8 Ah[4], Al[4];
#pragma unroll
        for (int of = 0; of < 4; ++of) {
            const size_t ao = (size_t)(m0 + of * 16 + l15) * K + k0 + lg * 8;
            Ah[of] = *(const short8*)(Ah_ + ao);
            Al[of] = *(const short8*)(Al_ + ao);
        }
#pragma unroll
        for (int nf = 0; nf < 8; ++nf) {
            const size_t bo = (size_t)(n0 + nf * 16 + l15) * K + k0 + lg * 8;
            short8 Bh = *(const short8*)(Bh_ + bo);
            short8 Bl = *(const short8*)(Bl_ + bo);
#pragma unroll
            for (int of = 0; of < 4; ++of) {
                acc[of][nf] =
                    __builtin_amdgcn_mfma_f32_16x16x32_bf16(Ah[of], Bh, acc[of][nf], 0, 0, 0);
                acc[of][nf] =
                    __builtin_amdgcn_mfma_f32_16x16x32_bf16(Ah[of], Bl, acc[of][nf], 0, 0, 0);
                acc[of][nf] =
                    __builtin_amdgcn_mfma_f32_16x16x32_bf16(Al[of], Bh, acc[of][nf], 0, 0, 0);
            }
        }
    }

#pragma unroll
    for (int of = 0; of < 4; ++of) {
        const int m4 = m0 + of * 16 + lg * 4;
        if (MODE == 0) {
#pragma unroll
            for (int nf = 0; nf < 8; ++nf) {
                const int n = n0 + nf * 16 + l15;
                *(f32x4*)(Pf + ((size_t)blockIdx.z * N + n) * M + m4) = acc[of][nf];
            }
        } else {
            float4 bv = *(const float4*)(bias + m4);
            float bva[4] = {bv.x, bv.y, bv.z, bv.w};
#pragma unroll
            for (int nf = 0; nf < 8; ++nf) {
                const int n = n0 + nf * 16 + l15;
                short4v hv, lv;
#pragma unroll
                for (int r = 0; r < 4; ++r) {
                    float v = acc[of][nf][r] + bva[r];
                    unsigned short hh, ll;
                    split2(v, hh, ll);
                    hv[r] = (short)hh;
                    lv[r] = (short)ll;
                }
                *(short4v*)(Oh + (size_t)n * M + m4) = hv;
                *(short4v*)(Ol + (size_t)n * M + m4) = lv;
            }
        }
    }
}

// sum 32 split-K partials [kz][b][e] + bias -> z [b][e]
__global__ void reduce_bias32(const float4* __restrict__ part, const float* __restrict__ bias,
                              float4* __restrict__ z) {
    int t = blockIdx.x * 256 + threadIdx.x;  // over B_*E_/4
    const size_t stride = (size_t)B_ * E_ / 4;
    float4 a = part[t];
#pragma unroll 4
    for (int s = 1; s < 32; ++s) {
        float4 p = part[(size_t)s * stride + t];
        a.x += p.x;
        a.y += p.y;
        a.z += p.z;
        a.w += p.w;
    }
    float4 bv = ((const float4*)bias)[t & (E_ / 4 - 1)];
    a.x += bv.x;
    a.y += bv.y;
    a.z += bv.z;
    a.w += bv.w;
    z[t] = a;
}

// ---------------- VQ (fp32, validated round-2) ----------------
__global__ void cnorm_k(const float* __restrict__ cb, float* __restrict__ cnorm) {
    int n = blockIdx.x;
    int l = threadIdx.x;
    const float4* row = (const float4*)(cb + (size_t)n * E_);
    float s = 0.f;
#pragma unroll
    for (int q = 0; q < 2; ++q) {
        float4 v = row[l + q * 64];
        s += v.x * v.x + v.y * v.y + v.z * v.z + v.w * v.w;
    }
#pragma unroll
    for (int off = 32; off; off >>= 1) s += __shfl_down(s, off);
    if (l == 0) cnorm[n] = s;
}

__global__ __launch_bounds__(256) void vq_score(const float* __restrict__ z,
                                                const float* __restrict__ cb,
                                                const float* __restrict__ cnorm,
                                                float* __restrict__ pval, int* __restrict__ pidx) {
    __shared__ __align__(16) float smem[2 * 16 * 132];
    float(*As)[132] = (float(*)[132])smem;
    float(*Bsh)[132] = (float(*)[132])(smem + 16 * 132);
    const int n0 = blockIdx.x * 128;
    const int m0 = blockIdx.y * 128;
    const int tid = threadIdx.x;
    const int tx = tid & 15;
    const int ty = tid >> 4;
    float acc[8][8] = {};

    for (int k0 = 0; k0 < E_; k0 += 16) {
#pragma unroll
        for (int l = 0; l < 2; ++l) {
            int t = tid + l * 256;
            int r = t >> 2;
            int c = (t & 3) << 2;
            float4 va = *(const float4*)(z + (size_t)(m0 + r) * E_ + k0 + c);
            As[c + 0][r] = va.x;
            As[c + 1][r] = va.y;
            As[c + 2][r] = va.z;
            As[c + 3][r] = va.w;
            float4 vb = *(const float4*)(cb + (size_t)(n0 + r) * E_ + k0 + c);
            Bsh[c + 0][r] = vb.x;
            Bsh[c + 1][r] = vb.y;
            Bsh[c + 2][r] = vb.z;
            Bsh[c + 3][r] = vb.w;
        }
        __syncthreads();
#pragma unroll
        for (int k = 0; k < 16; ++k) {
            float a[8], b[8];
            *(float4*)&a[0] = *(const float4*)&As[k][ty * 8];
            *(float4*)&a[4] = *(const float4*)&As[k][ty * 8 + 4];
            *(float4*)&b[0] = *(const float4*)&Bsh[k][tx * 8];
            *(float4*)&b[4] = *(const float4*)&Bsh[k][tx * 8 + 4];
#pragma unroll
            for (int i = 0; i < 8; ++i)
#pragma unroll
                for (int j = 0; j < 8; ++j) acc[i][j] += a[i] * b[j];
        }
        __syncthreads();
    }

    float* sv = smem;
    int* si = (int*)(smem + 16 * 132);
    float cn[8];
    *(float4*)&cn[0] = *(const float4*)(cnorm + n0 + tx * 8);
    *(float4*)&cn[4] = *(const float4*)(cnorm + n0 + tx * 8 + 4);
#pragma unroll
    for (int i = 0; i < 8; ++i) {
        int row = ty * 8 + i;
        float bvv = -3.4e38f;
        int bn = 0;
#pragma unroll
        for (int j = 0; j < 8; ++j) {
            float v = 2.f * acc[i][j] - cn[j];
            if (v > bvv) {
                bvv = v;
                bn = n0 + tx * 8 + j;
            }
        }
        sv[row * 16 + tx] = bvv;
        si[row * 16 + tx] = bn;
    }
    __syncthreads();
    if (tid < 128) {
        float bvv = sv[tid * 16];
        int bn = si[tid * 16];
#pragma unroll
        for (int t = 1; t < 16; ++t) {
            float v = sv[tid * 16 + t];
            if (v > bvv) {
                bvv = v;
                bn = si[tid * 16 + t];
            }
        }
        pval[(size_t)(m0 + tid) * 64 + blockIdx.x] = bvv;
        pidx[(size_t)(m0 + tid) * 64 + blockIdx.x] = bn;
    }
}

__global__ void vq_final(const float* __restrict__ pval, const int* __restrict__ pidx,
                         int* __restrict__ idx) {
    int b = blockIdx.x * 256 + threadIdx.x;
    if (b < B_) {
        const float* pv = pval + (size_t)b * 64;
        const int* pi = pidx + (size_t)b * 64;
        float bvv = pv[0];
        int bn = pi[0];
        for (int t = 1; t < 64; ++t) {
            float v = pv[t];
            if (v > bvv) {
                bvv = v;
                bn = pi[t];
            }
        }
        idx[b] = bn;
    }
}

// gather z_q -> hi/lo planes + per-row sum (zq-z)^2
__global__ __launch_bounds__(128) void zq_loss(const float* __restrict__ z,
                                               const float* __restrict__ cb,
                                               const int* __restrict__ idx,
                                               unsigned short* __restrict__ zqh,
                                               unsigned short* __restrict__ zql,
                                               float* __restrict__ lsum) {
    int b = blockIdx.x;
    int t = threadIdx.x;  // 128
    int id = idx[b];
    float4 c = ((const float4*)(cb + (size_t)id * E_))[t];
    float4 zv = ((const float4*)(z + (size_t)b * E_))[t];
    float ca[4] = {c.x, c.y, c.z, c.w};
    short4v hv, lv;
#pragma unroll
    for (int r = 0; r < 4; ++r) {
        unsigned short hh, ll;
        split2(ca[r], hh, ll);
        hv[r] = (short)hh;
        lv[r] = (short)ll;
    }
    *(short4v*)(zqh + (size_t)b * E_ + t * 4) = hv;
    *(short4v*)(zql + (size_t)b * E_ + t * 4) = lv;
    float dx = c.x - zv.x, dy = c.y - zv.y, dz = c.z - zv.z, dw = c.w - zv.w;
    float s = dx * dx + dy * dy + dz * dz + dw * dw;
#pragma unroll
    for (int off = 32; off; off >>= 1) s += __shfl_down(s, off);
    __shared__ float w2[2];
    if ((t & 63) == 0) w2[t >> 6] = s;
    __syncthreads();
    if (t == 0) lsum[b] = w2[0] + w2[1];
}

__global__ void loss_final(const float* __restrict__ lsum, float* __restrict__ out) {
    __shared__ float sm[256];
    float s = 0.f;
    for (int i = threadIdx.x; i < B_; i += 256) s += lsum[i];
    sm[threadIdx.x] = s;
    __syncthreads();
    for (int off = 128; off; off >>= 1) {
        if (threadIdx.x < off) sm[threadIdx.x] += sm[threadIdx.x + off];
        __syncthreads();
    }
    if (threadIdx.x == 0) out[0] = 1.25f * sm[0] / (float)(B_ * E_);
}

// ---------------- launcher ----------------
extern "C" void kernel_launch(void* const* d_in, const int* in_sizes, int n_in,
                              void* d_out, int out_size, void* d_ws, size_t ws_size,
                              hipStream_t stream) {
    const float* x = (const float*)d_in[0];
    const float* ew1 = (const float*)d_in[1];
    const float* eb1 = (const float*)d_in[2];
    const float* ew2 = (const float*)d_in[3];
    const float* eb2 = (const float*)d_in[4];
    const float* ew3 = (const float*)d_in[5];
    const float* eb3 = (const float*)d_in[6];
    const float* ew4 = (const float*)d_in[7];
    const float* eb4 = (const float*)d_in[8];
    const float* efw = (const float*)d_in[9];
    const float* efb = (const float*)d_in[10];
    const float* cb = (const float*)d_in[11];
    const float* dfw = (const float*)d_in[12];
    const float* dfb = (const float*)d_in[13];
    const float* dw4 = (const float*)d_in[14];
    const float* db4 = (const float*)d_in[15];
    const float* dw3 = (const float*)d_in[16];
    const float* db3 = (const float*)d_in[17];
    const float* dw2 = (const float*)d_in[18];
    const float* db2 = (const float*)d_in[19];
    const float* dw1 = (const float*)d_in[20];
    const float* db1 = (const float*)d_in[21];
    float* out = (float*)d_out;

    char* wp = (char*)d_ws;
    auto alloc = [&](size_t bytes) {
        char* p = wp;
        wp += (bytes + 255) & ~(size_t)255;
        return p;
    };
    unsigned short* actA_h = (unsigned short*)alloc(33554432);
    unsigned short* actA_l = (unsigned short*)alloc(33554432);
    unsigned short* actB_h = (unsigned short*)alloc(33554432);
    unsigned short* actB_l = (unsigned short*)alloc(33554432);
    float* partial = (float*)actB_h;  // 67.1 MB overlay (free at FC1 time)
    unsigned short* w1h = (unsigned short*)alloc(786432);
    unsigned short* w1l = (unsigned short*)alloc(786432);
    unsigned short* w2h = (unsigned short*)alloc(1572864);
    unsigned short* w2l = (unsigned short*)alloc(1572864);
    unsigned short* w3h = (unsigned short*)alloc(1572864);
    unsigned short* w3l = (unsigned short*)alloc(1572864);
    unsigned short* w4h = (unsigned short*)alloc(1572864);
    unsigned short* w4l = (unsigned short*)alloc(1572864);
    unsigned short* w5h = (unsigned short*)alloc(1572864);
    unsigned short* w5l = (unsigned short*)alloc(1572864);
    unsigned short* w6h = (unsigned short*)alloc(1572864);
    unsigned short* w6l = (unsigned short*)alloc(1572864);
    unsigned short* w7h = (unsigned short*)alloc(1572864);
    unsigned short* w7l = (unsigned short*)alloc(1572864);
    unsigned short* w8h = (unsigned short*)alloc(786432);
    unsigned short* w8l = (unsigned short*)alloc(786432);
    unsigned short* fcwh = (unsigned short*)alloc(16777216);  // efw' then dfw'
    unsigned short* fcwl = (unsigned short*)alloc(16777216);
    float* z = (float*)alloc(2097152);
    unsigned short* zqh = (unsigned short*)alloc(1048576);
    unsigned short* zql = (unsigned short*)alloc(1048576);
    float* cnorm = (float*)alloc(32768);
    float* pval = (float*)alloc(262144);
    int* pidx = (int*)alloc(262144);
    int* idx = (int*)alloc(4096);
    float* lsum = (float*)alloc(4096);
    float* dfbp = (float*)alloc(65536);

    // ---- preps ----
    transpose_split<<<1024, 256, 0, stream>>>(x, actA_h, actA_l, 1, 8192, 8192, 256);
    wprep_conv<<<512, 256, 0, stream>>>(ew1, w1h, w1l, 512, 256);
    wprep_conv<<<1024, 256, 0, stream>>>(ew2, w2h, w2l, 512, 512);
    wprep_conv<<<1024, 256, 0, stream>>>(ew3, w3h, w3l, 512, 512);
    wprep_conv<<<1024, 256, 0, stream>>>(ew4, w4h, w4l, 512, 512);
    wprep_deconv<<<1024, 256, 0, stream>>>(dw4, w5h, w5l, 512, 512);
    wprep_deconv<<<1024, 256, 0, stream>>>(dw3, w6h, w6l, 512, 512);
    wprep_deconv<<<1024, 256, 0, stream>>>(dw2, w7h, w7l, 512, 512);
    wprep_deconv<<<512, 256, 0, stream>>>(dw1, w8h, w8l, 256, 512);
    wprep_dfb<<<64, 256, 0, stream>>>(dfb, dfbp);
    transpose_split<<<1024, 256, 0, stream>>>(efw, fcwh, fcwl, 2, 16384, 16384, 512);

    // ---- encoder ----
    conv_mfma<256, 512, false><<<256, 512, 0, stream>>>(actA_h, actA_l, w1h, w1l, eb1,
                                                        actB_h, actB_l, nullptr);
    conv_mfma<512, 512, false><<<256, 512, 0, stream>>>(actB_h, actB_l, w2h, w2l, eb2,
                                                        actA_h, actA_l, nullptr);
    conv_mfma<512, 512, false><<<256, 512, 0, stream>>>(actA_h, actA_l, w3h, w3l, eb3,
                                                        actB_h, actB_l, nullptr);
    conv_mfma<512, 512, false><<<256, 512, 0, stream>>>(actB_h, actB_l, w4h, w4l, eb4,
                                                        actA_h, actA_l, nullptr);
    // enc FC: M=512(e), N=1024(b), K=16384, split-K 32
    fc_mfma<0><<<dim3(4, 2, 32), 512, 0, stream>>>(fcwh, fcwl, actA_h, actA_l, nullptr,
                                                   partial, nullptr, nullptr, 512, 1024,
                                                   16384, 512);
    reduce_bias32<<<512, 256, 0, stream>>>((const float4*)partial, efb, (float4*)z);

    // ---- VQ (fp32) ----
    cnorm_k<<<NE_, 64, 0, stream>>>(cb, cnorm);
    vq_score<<<dim3(64, 8), 256, 0, stream>>>(z, cb, cnorm, pval, pidx);
    vq_final<<<4, 256, 0, stream>>>(pval, pidx, idx);
    zq_loss<<<B_, 128, 0, stream>>>(z, cb, idx, zqh, zql, lsum);
    loss_final<<<1, 256, 0, stream>>>(lsum, out + (size_t)B_ * IN_ * T_);

    // ---- decoder ----
    wprep_dfw<<<4096, 256, 0, stream>>>(dfw, fcwh, fcwl);  // reuse fcw slot
    // dec FC: M=16384(f'), N=1024(b), K=512 -> g planes [b][f'] in actB
    fc_mfma<1><<<dim3(4, 64, 1), 512, 0, stream>>>(fcwh, fcwl, zqh, zql, dfbp, nullptr,
                                                   actB_h, actB_l, 16384, 1024, 512, 512);
    conv_mfma<512, 512, false><<<256, 512, 0, stream>>>(actB_h, actB_l, w5h, w5l, db4,
                                                        actA_h, actA_l, nullptr);
    conv_mfma<512, 512, false><<<256, 512, 0, stream>>>(actA_h, actA_l, w6h, w6l, db3,
                                                        actB_h, actB_l, nullptr);
    conv_mfma<512, 512, false><<<256, 512, 0, stream>>>(actB_h, actB_l, w7h, w7l, db2,
                                                        actA_h, actA_l, nullptr);
    conv_mfma<512, 256, true><<<256, 512, 0, stream>>>(actA_h, actA_l, w8h, w8l, db1,
                                                       nullptr, nullptr, out);
}